// Round 19
// baseline (184.840 us; speedup 1.0000x reference)
//
#include <hip/hip_runtime.h>

typedef short short8 __attribute__((ext_vector_type(8)));
typedef unsigned short ushort8v __attribute__((ext_vector_type(8)));
typedef float f32x4 __attribute__((ext_vector_type(4)));

static __device__ __forceinline__ unsigned short f2b(float f) {
    unsigned int u = __builtin_bit_cast(unsigned int, f);
    unsigned int r = (u + 0x7fffu + ((u >> 16) & 1u)) >> 16;
    return (unsigned short)r;
}
static __device__ __forceinline__ float b2f(unsigned short u) {
    return __builtin_bit_cast(float, (unsigned int)u << 16);
}
static __device__ __forceinline__ float exp2v(float x) {
    float r;
    asm("v_exp_f32 %0, %1" : "=v"(r) : "v"(x));
    return r;
}
static __device__ __forceinline__ unsigned cvt_pk_bf16(float lo, float hi) {
    unsigned r;
    asm("v_cvt_pk_bf16_f32 %0, %1, %2" : "=v"(r) : "v"(lo), "v"(hi));
    return r;
}

__device__ __forceinline__ void gload16(void* lds, const void* g) {
    __builtin_amdgcn_global_load_lds(
        (const __attribute__((address_space(1))) void*)g,
        (__attribute__((address_space(3))) void*)lds, 16, 0, 0);
}

#define L2E 1.4426950408889634f

// ---------------- fused prep: cvt x (f32->bf16) + 4 weight transposes ----------------
__global__ __launch_bounds__(256) void prep_kernel(
    const float* __restrict__ x, unsigned short* __restrict__ xb,
    const float* __restrict__ qkv_w, unsigned short* __restrict__ qwT,
    const float* __restrict__ out_w, unsigned short* __restrict__ owT,
    const float* __restrict__ ff1_w, unsigned short* __restrict__ f1T,
    const float* __restrict__ ff2_w, unsigned short* __restrict__ f2T) {
    const int bx = blockIdx.x;
    const int tid = threadIdx.x;
    if (bx < 6144) {  // cvt x
        int i = bx * 256 + tid;
        float4 f = ((const float4*)x)[i];
        ushort4 u;
        u.x = f2b(f.x); u.y = f2b(f.y); u.z = f2b(f.z); u.w = f2b(f.w);
        ((ushort4*)xb)[i] = u;
        return;
    }
    __shared__ float t[32][33];
    int rb = bx - 6144;
    const float* W; unsigned short* Wt; int K, N;
    if (rb < 1728)      { W = qkv_w; Wt = qwT; K = 768;  N = 2304; }
    else if (rb < 2304) { rb -= 1728; W = out_w; Wt = owT; K = 768;  N = 768; }
    else if (rb < 3072) { rb -= 2304; W = ff1_w; Wt = f1T; K = 768;  N = 1024; }
    else                { rb -= 3072; W = ff2_w; Wt = f2T; K = 1024; N = 768; }
    const int nbl = N / 32;
    const int nb = (rb % nbl) * 32, kb = (rb / nbl) * 32;
    const int tx = tid & 31, ty = tid >> 5;
#pragma unroll
    for (int i = 0; i < 32; i += 8)
        t[ty + i][tx] = W[(size_t)(kb + ty + i) * N + nb + tx];
    __syncthreads();
#pragma unroll
    for (int i = 0; i < 32; i += 8)
        Wt[(size_t)(nb + ty + i) * K + kb + tx] = f2b(t[tx][ty + i]);
}

// ---------------- 128x128 BK=32 2-phase GEMM, 8 waves, 32KB LDS -> 4 blocks/CU ---------
// EPI: 0 = f32 out, 1 = bf16 out, 2 = gelu->bf16 out, 3 = qkv scatter (width-96 Q/K)
// Same proven 2-phase skeleton as r15/r17 (stage(t+1) -> compute(t) -> vmcnt(0) -> barrier);
// only the K-depth halved so 4 blocks co-reside per CU (32 waves = full occupancy, m114).
template <int EPI>
__global__ __launch_bounds__(512, 8) void gemm2p(
    const unsigned short* __restrict__ A, const unsigned short* __restrict__ Bt,
    const float* __restrict__ bias, float* __restrict__ outf,
    unsigned short* __restrict__ outb, unsigned short* __restrict__ q_o,
    unsigned short* __restrict__ k_o, unsigned short* __restrict__ v_o,
    int N, int K, int ntn, int NT) {
    __shared__ unsigned short a_lds[2][4096];
    __shared__ unsigned short b_lds[2][4096];
    const int tid = threadIdx.x;
    const int wave = tid >> 6, lane = tid & 63;
    const int lr = lane & 15, lg = lane >> 4;
    const int wm = wave >> 2, wn = wave & 3;
    const int nwg = gridDim.x;
    const int orig = blockIdx.x;
    const int swz = (orig & 7) * (nwg >> 3) + (orig >> 3);
    const int tm = swz / ntn, tn = swz % ntn;

    // granule g = tid: row = g>>2, sl = g&3, src col-granule = sl ^ ((row>>1)&3)
    const int grow = tid >> 2;
    const int gcol = (tid & 3) ^ ((grow >> 1) & 3);
    const unsigned short* srcA = A + (size_t)(tm * 128 + grow) * K + gcol * 8;
    const unsigned short* srcB = Bt + (size_t)(tn * 128 + grow) * K + gcol * 8;
    auto stage = [&](int buf, int t) {
        gload16(&a_lds[buf][wave * 512], srcA + t * 32);
        gload16(&b_lds[buf][wave * 512], srcB + t * 32);
    };

    f32x4 acc[4][2] = {};

    stage(0, 0);
    asm volatile("s_waitcnt vmcnt(0)" ::: "memory");
    __builtin_amdgcn_s_barrier();

    for (int t = 0; t < NT; ++t) {
        const int buf = t & 1;
        if (t + 1 < NT) stage(buf ^ 1, t + 1);
        short8 af[4], bfr[2];
#pragma unroll
        for (int mf = 0; mf < 4; ++mf) {
            int row = wm * 64 + mf * 16 + lr;
            int slot = lg ^ ((row >> 1) & 3);
            af[mf] = *(const short8*)&a_lds[buf][row * 32 + slot * 8];
        }
#pragma unroll
        for (int nf = 0; nf < 2; ++nf) {
            int row = wn * 32 + nf * 16 + lr;
            int slot = lg ^ ((row >> 1) & 3);
            bfr[nf] = *(const short8*)&b_lds[buf][row * 32 + slot * 8];
        }
#pragma unroll
        for (int mf = 0; mf < 4; ++mf)
#pragma unroll
            for (int nf = 0; nf < 2; ++nf)
                acc[mf][nf] = __builtin_amdgcn_mfma_f32_16x16x32_bf16(af[mf], bfr[nf], acc[mf][nf], 0, 0, 0);
        asm volatile("s_waitcnt vmcnt(0)" ::: "memory");
        __builtin_amdgcn_s_barrier();
    }

#pragma unroll
    for (int nf = 0; nf < 2; ++nf) {
        int gc = tn * 128 + wn * 32 + nf * 16 + lr;
        float bv = bias[gc];
        int part = 0, h = 0, dh = 0;
        if constexpr (EPI == 3) {
            part = gc / 768;
            int cc = gc - part * 768;
            h = cc / 96;
            dh = cc - h * 96;
        }
#pragma unroll
        for (int mf = 0; mf < 4; ++mf) {
            int grb = tm * 128 + wm * 64 + mf * 16 + lg * 4;
            if constexpr (EPI == 3) {
                int b = grb >> 10, n2 = grb & 1023;
                size_t bh = (size_t)(b * 8 + h);
                if (part == 2) {
                    ushort4 wv;
                    wv.x = f2b(acc[mf][nf][0] + bv);
                    wv.y = f2b(acc[mf][nf][1] + bv);
                    wv.z = f2b(acc[mf][nf][2] + bv);
                    wv.w = f2b(acc[mf][nf][3] + bv);
                    *(ushort4*)&v_o[(bh * 96 + dh) * 1024 + n2] = wv;
                } else {
                    unsigned short* dst = (part == 0) ? q_o : k_o;
                    float sc = (part == 0) ? 0.14724445f : 1.f;
#pragma unroll
                    for (int r = 0; r < 4; ++r)
                        dst[(bh * 1024 + n2 + r) * 96 + dh] = f2b((acc[mf][nf][r] + bv) * sc);
                }
            } else {
#pragma unroll
                for (int r = 0; r < 4; ++r) {
                    int gr = grb + r;
                    float v = acc[mf][nf][r] + bv;
                    if constexpr (EPI == 0) {
                        outf[(size_t)gr * N + gc] = v;
                    } else if constexpr (EPI == 1) {
                        outb[(size_t)gr * N + gc] = f2b(v);
                    } else {
                        float gl = 0.5f * v * (1.f + erff(v * 0.70710678f));
                        outb[(size_t)gr * N + gc] = f2b(gl);
                    }
                }
            }
        }
    }
}

// ---------------- flash attention: swapped QK^T, hoisted cjmm, folded flat-re, T5 ------
// (byte-identical to round 17)
__global__ __launch_bounds__(512, 4) void attn_kernel(
    const unsigned short* __restrict__ Qb, const unsigned short* __restrict__ Kb,
    const unsigned short* __restrict__ Vt, const float* __restrict__ centers,
    const int* __restrict__ types, const int* __restrict__ nmask,
    const float* __restrict__ tt, const float* __restrict__ rel_emb,
    unsigned short* __restrict__ Y) {
    __shared__ unsigned short kv_lds[2 * 12288];  // 48 KB
    __shared__ unsigned short p_lds[8 * 1024];    // 16 KB
    __shared__ float c_lds[1024];
    __shared__ unsigned int bab_lds[1024];
    __shared__ float rel_lds[41];
    __shared__ float cjmm_lds[32];

    const int tid = threadIdx.x;
    const int wave = tid >> 6, lane = tid & 63;
    const int lr = lane & 15, lg = lane >> 4;
    const int bh = blockIdx.x, qb = blockIdx.y;
    const int b = bh >> 3, h = bh & 7;
    const int q0 = qb * 128 + wave * 16;
    const size_t kvbase = (size_t)bh * 1024 * 96;

    c_lds[tid] = centers[b * 1024 + tid];
    c_lds[tid + 512] = centers[b * 1024 + 512 + tid];
    if (tid < 41) rel_lds[tid] = rel_emb[tid * 8 + h] * L2E;
    {
        const float t00 = tt[h * 4], t01 = tt[h * 4 + 1];
        const float t10 = tt[h * 4 + 2], t11 = tt[h * 4 + 3];
#pragma unroll
        for (int i = 0; i < 2; ++i) {
            int j = tid + i * 512;
            int tj = types[b * 1024 + j];
            int mk = nmask[b * 1024 + j];
            float bA = L2E * (t00 + (t01 - t00) * tj) + (mk ? 0.f : -1e30f);
            float bB = L2E * ((t10 - t00) + (t11 - t01 - t10 + t00) * tj);
            bab_lds[j] = (unsigned)f2b(bA) | ((unsigned)f2b(bB) << 16);
        }
    }

    const unsigned short* sbase[3];
    int sstep[3];
#pragma unroll
    for (int it = 0; it < 3; ++it) {
        int g = it * 512 + tid;
        if (g < 768) {  // K granule
            int ks = g >> 8, rem = g & 255, pr = rem >> 3, sl = rem & 7;
            int so = sl ^ (pr & 7);
            int r = ((so >> 2) << 5) + pr, oct = so & 3;
            sbase[it] = Kb + kvbase + (size_t)r * 96 + ks * 32 + oct * 8;
            sstep[it] = 64 * 96;
        } else {  // V granule
            int gv = g - 768, pr = gv >> 3, sl = gv & 7;
            int so = sl ^ (pr & 7);
            sbase[it] = Vt + (size_t)(bh * 96 + pr) * 1024 + so * 8;
            sstep[it] = 64;
        }
    }
    auto stage = [&](int bufb, int kt) {
        unsigned short* dst = kv_lds + bufb * 12288;
#pragma unroll
        for (int it = 0; it < 3; ++it)
            gload16(dst + it * 4096 + wave * 512, sbase[it] + (size_t)kt * sstep[it]);
    };

    short8 qa[3];
#pragma unroll
    for (int ks = 0; ks < 3; ++ks)
        qa[ks] = *(const short8*)&Qb[kvbase + (size_t)(q0 + lr) * 96 + ks * 32 + lg * 8];
    short8 qa3 = {};
    {
        int ti0 = types[b * 1024 + q0 + lr];
        if (lg == 0) {
            qa3[0] = (short)0x3F80;
            qa3[1] = ti0 ? (short)0x3F80 : (short)0;
        }
    }
    const float ci20 = centers[b * 1024 + q0 + lr] + 20.f;
    float cimax20 = ci20, cimin20 = ci20;
#pragma unroll
    for (int off = 1; off < 16; off <<= 1) {
        cimax20 = fmaxf(cimax20, __shfl_xor(cimax20, off));
        cimin20 = fminf(cimin20, __shfl_xor(cimin20, off));
    }

    float m_s = -3e30f, l_s = 0.f;
    f32x4 oacc[6] = {};
    unsigned* p32 = (unsigned*)&p_lds[wave * 1024];

    stage(0, 0);
    asm volatile("s_waitcnt lgkmcnt(0)" ::: "memory");
    __builtin_amdgcn_s_barrier();

    if (tid < 256) {
        int ktt = tid >> 4;
        float4 cv = *(const float4*)&c_lds[ktt * 64 + (tid & 15) * 4];
        float mn = fminf(fminf(cv.x, cv.y), fminf(cv.z, cv.w));
        float mx = fmaxf(fmaxf(cv.x, cv.y), fmaxf(cv.z, cv.w));
#pragma unroll
        for (int off = 1; off < 16; off <<= 1) {
            mn = fminf(mn, __shfl_xor(mn, off));
            mx = fmaxf(mx, __shfl_xor(mx, off));
        }
        if ((tid & 15) == 0) { cjmm_lds[ktt] = mn; cjmm_lds[16 + ktt] = mx; }
    }
    asm volatile("s_waitcnt lgkmcnt(0)" ::: "memory");
    const float rel0v = rel_lds[0], rel40v = rel_lds[40];

    for (int kt = 0; kt < 16; ++kt) {
        const int buf = kt & 1;
        if (kt < 15) {
            stage(buf ^ 1, kt + 1);
            asm volatile("s_waitcnt vmcnt(3)" ::: "memory");
        } else {
            asm volatile("s_waitcnt vmcnt(0)" ::: "memory");
        }
        __builtin_amdgcn_s_barrier();
        const unsigned short* kv = kv_lds + buf * 12288;

        f32x4 s[4] = {};
        __builtin_amdgcn_s_setprio(1);
#pragma unroll
        for (int jf = 0; jf < 4; ++jf) {
            int pr = ((jf & 1) << 4) + lr;
            int slp = (((jf >> 1) << 2) + lg) ^ (lr & 7);
#pragma unroll
            for (int ks = 0; ks < 3; ++ks) {
                short8 kf = *(const short8*)&kv[ks * 2048 + pr * 64 + slp * 8];
                s[jf] = __builtin_amdgcn_mfma_f32_16x16x32_bf16(kf, qa[ks], s[jf], 0, 0, 0);
            }
            unsigned vb = bab_lds[kt * 64 + jf * 16 + lr];
            short8 kf3 = {};
            if (lg == 0) {
                kf3[0] = (short)(vb & 0xffffu);
                kf3[1] = (short)(vb >> 16);
            }
            s[jf] = __builtin_amdgcn_mfma_f32_16x16x32_bf16(kf3, qa3, s[jf], 0, 0, 0);
        }
        __builtin_amdgcn_s_setprio(0);

        float re_eff;
        {
            float cjmn = cjmm_lds[kt], cjmx = cjmm_lds[16 + kt];
            bool flatHi = (cimin20 - cjmx >= 40.f);
            bool flatLo = (cimax20 - cjmn <= 0.f);
            if (flatHi || flatLo) {
                re_eff = flatHi ? rel40v : rel0v;
            } else {
                re_eff = 0.f;
#pragma unroll
                for (int jf = 0; jf < 4; ++jf) {
                    float4 cj4 = *(const float4*)&c_lds[kt * 64 + jf * 16 + lg * 4];
                    float cjl[4] = {cj4.x, cj4.y, cj4.z, cj4.w};
#pragma unroll
                    for (int r = 0; r < 4; ++r) {
                        float idxf = __builtin_amdgcn_fmed3f(ci20 - cjl[r], 0.f, 40.f);
                        s[jf][r] += rel_lds[(int)rintf(idxf)];
                    }
                }
            }
        }

        {
            float mlr = s[0][0];
#pragma unroll
            for (int jf = 0; jf < 4; ++jf)
#pragma unroll
                for (int r = 0; r < 4; ++r) mlr = fmaxf(mlr, s[jf][r]);
            float mb = m_s - re_eff;
            if (!__all(mlr <= mb + 8.f)) {
                float mx = fmaxf(mlr, __shfl_xor(mlr, 16));
                mx = fmaxf(mx, __shfl_xor(mx, 32));
                mx += re_eff;
                float mn = fmaxf(m_s, mx);
                float al = exp2v(m_s - mn);
                m_s = mn;
                l_s *= al;
#pragma unroll
                for (int r = 0; r < 4; ++r) {
                    float alr = __shfl(al, lg * 4 + r);
#pragma unroll
                    for (int nf = 0; nf < 6; ++nf) oacc[nf][r] *= alr;
                }
                mb = m_s - re_eff;
            }
            float ls = 0.f;
#pragma unroll
            for (int jf = 0; jf < 4; ++jf)
#pragma unroll
                for (int r = 0; r < 4; ++r) {
                    s[jf][r] = exp2v(s[jf][r] - mb);
                    ls += s[jf][r];
                }
            ls += __shfl_xor(ls, 16);
            ls += __shfl_xor(ls, 32);
            l_s += ls;
        }

#pragma unroll
        for (int jf = 0; jf < 4; ++jf) {
            uint2 w2;
            w2.x = cvt_pk_bf16(s[jf][0], s[jf][1]);
            w2.y = cvt_pk_bf16(s[jf][2], s[jf][3]);
            int gsw = ((jf * 4 + lg) ^ (lr & 14)) * 2;
            *(uint2*)&p32[lr * 32 + gsw] = w2;
        }
        asm volatile("s_waitcnt lgkmcnt(0)" ::: "memory");
        short8 pa[2];
#pragma unroll
        for (int js = 0; js < 2; ++js) {
            int gsw = (((js * 8 + lg * 2) ^ (lr & 14))) * 2;
            pa[js] = *(const short8*)&p32[lr * 32 + gsw];
        }

        __builtin_amdgcn_s_setprio(1);
#pragma unroll
        for (int nf = 0; nf < 6; ++nf) {
            int vrow = nf * 16 + lr;
#pragma unroll
            for (int js = 0; js < 2; ++js) {
                int slp = ((js << 2) + lg) ^ (lr & 7);
                short8 vf = *(const short8*)&kv[6144 + vrow * 64 + slp * 8];
                oacc[nf] = __builtin_amdgcn_mfma_f32_16x16x32_bf16(pa[js], vf, oacc[nf], 0, 0, 0);
            }
        }
        __builtin_amdgcn_s_setprio(0);
        __builtin_amdgcn_s_barrier();
    }

#pragma unroll
    for (int r = 0; r < 4; ++r) {
        float lrow = __shfl(l_s, lg * 4 + r);
        float inv = (lrow > 0.f) ? 1.f / lrow : 0.f;
        int qi = q0 + lg * 4 + r;
#pragma unroll
        for (int nf = 0; nf < 6; ++nf)
            Y[((size_t)b * 1024 + qi) * 768 + h * 96 + nf * 16 + lr] = f2b(oacc[nf][r] * inv);
    }
}

// ---------------- layernorm with residual add (vectorized, 2 rows/block) ----------------
template <bool IN1BF, bool IN2BF>
__global__ __launch_bounds__(384) void ln_kernel(const void* __restrict__ in1,
                                                 const void* __restrict__ in2,
                                                 const float* __restrict__ g,
                                                 const float* __restrict__ be,
                                                 float* __restrict__ of,
                                                 unsigned short* __restrict__ ob) {
    const int tid = threadIdx.x;
    const int half = tid / 192;
    const int t = tid - half * 192;
    const int row = blockIdx.x * 2 + half;
    const size_t base = (size_t)row * 768 + t * 4;
    float a[4], bb[4];
    if (IN1BF) {
        ushort4 u = *(const ushort4*)((const unsigned short*)in1 + base);
        a[0] = b2f(u.x); a[1] = b2f(u.y); a[2] = b2f(u.z); a[3] = b2f(u.w);
    } else {
        float4 u = *(const float4*)((const float*)in1 + base);
        a[0] = u.x; a[1] = u.y; a[2] = u.z; a[3] = u.w;
    }
    if (IN2BF) {
        ushort4 u = *(const ushort4*)((const unsigned short*)in2 + base);
        bb[0] = b2f(u.x); bb[1] = b2f(u.y); bb[2] = b2f(u.z); bb[3] = b2f(u.w);
    } else {
        float4 u = *(const float4*)((const float*)in2 + base);
        bb[0] = u.x; bb[1] = u.y; bb[2] = u.z; bb[3] = u.w;
    }
    float v[4];
#pragma unroll
    for (int i = 0; i < 4; ++i) v[i] = a[i] + bb[i];
    float s1 = v[0] + v[1] + v[2] + v[3];
    float s2 = v[0] * v[0] + v[1] * v[1] + v[2] * v[2] + v[3] * v[3];
#pragma unroll
    for (int off = 32; off > 0; off >>= 1) {
        s1 += __shfl_xor(s1, off);
        s2 += __shfl_xor(s2, off);
    }
    __shared__ float red[12];
    const int wv = tid >> 6;
    if ((tid & 63) == 0) { red[wv] = s1; red[6 + wv] = s2; }
    __syncthreads();
    const int w0 = half * 3;
    s1 = red[w0] + red[w0 + 1] + red[w0 + 2];
    s2 = red[6 + w0] + red[6 + w0 + 1] + red[6 + w0 + 2];
    float mu = s1 * (1.f / 768.f);
    float var = s2 * (1.f / 768.f) - mu * mu;
    float inv = rsqrtf(var + 1e-5f);
    float o[4];
#pragma unroll
    for (int i = 0; i < 4; ++i)
        o[i] = (v[i] - mu) * inv * g[t * 4 + i] + be[t * 4 + i];
    if (of) {
        float4 w = {o[0], o[1], o[2], o[3]};
        *(float4*)(of + base) = w;
    }
    if (ob) {
        ushort4 w = {f2b(o[0]), f2b(o[1]), f2b(o[2]), f2b(o[3])};
        *(ushort4*)(ob + base) = w;
    }
}

extern "C" void kernel_launch(void* const* d_in, const int* in_sizes, int n_in,
                              void* d_out, int out_size, void* d_ws, size_t ws_size,
                              hipStream_t stream) {
    const float* x     = (const float*)d_in[0];
    const int*   nmask = (const int*)d_in[1];
    const float* cent  = (const float*)d_in[2];
    const int*   types = (const int*)d_in[3];
    const float* qkv_w = (const float*)d_in[4];
    const float* qkv_b = (const float*)d_in[5];
    const float* out_w = (const float*)d_in[6];
    const float* out_b = (const float*)d_in[7];
    const float* ff1_w = (const float*)d_in[8];
    const float* ff1_b = (const float*)d_in[9];
    const float* ff2_w = (const float*)d_in[10];
    const float* ff2_b = (const float*)d_in[11];
    const float* ln1_g = (const float*)d_in[12];
    const float* ln1_b = (const float*)d_in[13];
    const float* ln2_g = (const float*)d_in[14];
    const float* ln2_b = (const float*)d_in[15];
    const float* rel   = (const float*)d_in[16];
    const float* ttp   = (const float*)d_in[17];

    char* w = (char*)d_ws;
    auto alloc = [&](size_t bytes) {
        char* p = w;
        w += (bytes + 255) & ~(size_t)255;
        return p;
    };
    unsigned short* xb  = (unsigned short*)alloc(8192ull * 768 * 2);   // x bf16 (NOT clobbered)
    unsigned short* yb  = (unsigned short*)alloc(8192ull * 768 * 2);   // attn output Y
    unsigned short* qwT = (unsigned short*)alloc(2304ull * 768 * 2);
    unsigned short* owT = (unsigned short*)alloc(768ull * 768 * 2);
    unsigned short* f1T = (unsigned short*)alloc(1024ull * 768 * 2);
    unsigned short* f2T = (unsigned short*)alloc(768ull * 1024 * 2);
    unsigned short* Qb  = (unsigned short*)alloc(64ull * 1024 * 96 * 2);
    unsigned short* Kb  = (unsigned short*)alloc(64ull * 1024 * 96 * 2);
    unsigned short* Vt  = (unsigned short*)alloc(64ull * 96 * 1024 * 2);
    unsigned short* aob = (unsigned short*)alloc(8192ull * 768 * 2);  // residual branch (bf16)
    unsigned short* h1b = (unsigned short*)alloc(8192ull * 768 * 2);
    unsigned short* ffa = Qb;  // alias: ff1 act (16.8MB) spans Qb+Kb (25.2MB), both dead after attn

    // fused cvt + 4 transposes: 6144 + 3840 = 9984 blocks
    prep_kernel<<<9984, 256, 0, stream>>>(x, xb, qkv_w, qwT, out_w, owT,
                                          ff1_w, f1T, ff2_w, f2T);

    // QKV: M=8192 N=2304 K=768 -> 1152 blocks, NT=24
    gemm2p<3><<<1152, 512, 0, stream>>>(xb, qwT, qkv_b, nullptr, nullptr,
                                        Qb, Kb, Vt, 2304, 768, 18, 24);
    attn_kernel<<<dim3(64, 8), 512, 0, stream>>>(Qb, Kb, Vt, cent, types, nmask, ttp, rel, yb);
    // out proj: N=768 K=768 -> 384 blocks, NT=24, bf16 out
    gemm2p<1><<<384, 512, 0, stream>>>(yb, owT, out_b, nullptr, aob,
                                       nullptr, nullptr, nullptr, 768, 768, 6, 24);
    ln_kernel<true, true><<<4096, 384, 0, stream>>>(xb, aob, ln1_g, ln1_b, nullptr, h1b);
    // ff1+gelu: N=1024 K=768 -> 512 blocks, NT=24
    gemm2p<2><<<512, 512, 0, stream>>>(h1b, f1T, ff1_b, nullptr, ffa,
                                       nullptr, nullptr, nullptr, 1024, 768, 8, 24);
    // ff2: N=768 K=1024 -> 384 blocks, NT=32, bf16 out (reuse aob)
    gemm2p<1><<<384, 512, 0, stream>>>(ffa, f2T, ff2_b, nullptr, aob,
                                       nullptr, nullptr, nullptr, 768, 1024, 6, 32);
    ln_kernel<true, true><<<4096, 384, 0, stream>>>(h1b, aob, ln2_g, ln2_b, (float*)d_out, nullptr);
}

// Round 20
// 179.730 us; speedup vs baseline: 1.0284x; 1.0284x over previous
//
#include <hip/hip_runtime.h>

typedef short short8 __attribute__((ext_vector_type(8)));
typedef unsigned short ushort8v __attribute__((ext_vector_type(8)));
typedef float f32x4 __attribute__((ext_vector_type(4)));

static __device__ __forceinline__ unsigned short f2b(float f) {
    unsigned int u = __builtin_bit_cast(unsigned int, f);
    unsigned int r = (u + 0x7fffu + ((u >> 16) & 1u)) >> 16;
    return (unsigned short)r;
}
static __device__ __forceinline__ float b2f(unsigned short u) {
    return __builtin_bit_cast(float, (unsigned int)u << 16);
}
static __device__ __forceinline__ float exp2v(float x) {
    float r;
    asm("v_exp_f32 %0, %1" : "=v"(r) : "v"(x));
    return r;
}
static __device__ __forceinline__ unsigned cvt_pk_bf16(float lo, float hi) {
    unsigned r;
    asm("v_cvt_pk_bf16_f32 %0, %1, %2" : "=v"(r) : "v"(lo), "v"(hi));
    return r;
}

__device__ __forceinline__ void gload16(void* lds, const void* g) {
    __builtin_amdgcn_global_load_lds(
        (const __attribute__((address_space(1))) void*)g,
        (__attribute__((address_space(3))) void*)lds, 16, 0, 0);
}

#define L2E 1.4426950408889634f

// ---------------- fused prep: cvt x (f32->bf16) + 4 weight transposes ----------------
__global__ __launch_bounds__(256) void prep_kernel(
    const float* __restrict__ x, unsigned short* __restrict__ xb,
    const float* __restrict__ qkv_w, unsigned short* __restrict__ qwT,
    const float* __restrict__ out_w, unsigned short* __restrict__ owT,
    const float* __restrict__ ff1_w, unsigned short* __restrict__ f1T,
    const float* __restrict__ ff2_w, unsigned short* __restrict__ f2T) {
    const int bx = blockIdx.x;
    const int tid = threadIdx.x;
    if (bx < 6144) {  // cvt x
        int i = bx * 256 + tid;
        float4 f = ((const float4*)x)[i];
        ushort4 u;
        u.x = f2b(f.x); u.y = f2b(f.y); u.z = f2b(f.z); u.w = f2b(f.w);
        ((ushort4*)xb)[i] = u;
        return;
    }
    __shared__ float t[32][33];
    int rb = bx - 6144;
    const float* W; unsigned short* Wt; int K, N;
    if (rb < 1728)      { W = qkv_w; Wt = qwT; K = 768;  N = 2304; }
    else if (rb < 2304) { rb -= 1728; W = out_w; Wt = owT; K = 768;  N = 768; }
    else if (rb < 3072) { rb -= 2304; W = ff1_w; Wt = f1T; K = 768;  N = 1024; }
    else                { rb -= 3072; W = ff2_w; Wt = f2T; K = 1024; N = 768; }
    const int nbl = N / 32;
    const int nb = (rb % nbl) * 32, kb = (rb / nbl) * 32;
    const int tx = tid & 31, ty = tid >> 5;
#pragma unroll
    for (int i = 0; i < 32; i += 8)
        t[ty + i][tx] = W[(size_t)(kb + ty + i) * N + nb + tx];
    __syncthreads();
#pragma unroll
    for (int i = 0; i < 32; i += 8)
        Wt[(size_t)(nb + ty + i) * K + kb + tx] = f2b(t[tx][ty + i]);
}

// ---------------- 128x128 BK=64 2-phase GEMM, 8 waves (64x32 per wave) ----------------
// EPI: 0 = f32 out, 1 = bf16 out, 2 = gelu->bf16 out, 3 = qkv scatter (width-96 Q/K)
template <int EPI>
__global__ __launch_bounds__(512, 4) void gemm2p(
    const unsigned short* __restrict__ A, const unsigned short* __restrict__ Bt,
    const float* __restrict__ bias, float* __restrict__ outf,
    unsigned short* __restrict__ outb, unsigned short* __restrict__ q_o,
    unsigned short* __restrict__ k_o, unsigned short* __restrict__ v_o,
    int N, int K, int ntn, int NT) {
    __shared__ unsigned short a_lds[2][8192];
    __shared__ unsigned short b_lds[2][8192];
    const int tid = threadIdx.x;
    const int wave = tid >> 6, lane = tid & 63;
    const int lr = lane & 15, lg = lane >> 4;
    const int wm = wave >> 2, wn = wave & 3;
    const int nwg = gridDim.x;
    const int orig = blockIdx.x;
    const int swz = (orig & 7) * (nwg >> 3) + (orig >> 3);
    const int tm = swz / ntn, tn = swz % ntn;

    const unsigned short* srcA[2];
    const unsigned short* srcB[2];
#pragma unroll
    for (int i = 0; i < 2; ++i) {
        int g = i * 512 + tid;
        int row = g >> 3, sl = g & 7;
        int colg = sl ^ (row & 7);
        srcA[i] = A + (size_t)(tm * 128 + row) * K + colg * 8;
        srcB[i] = Bt + (size_t)(tn * 128 + row) * K + colg * 8;
    }
    auto stage = [&](int buf, int k0) {
#pragma unroll
        for (int i = 0; i < 2; ++i) {
            gload16(&a_lds[buf][i * 4096 + wave * 512], srcA[i] + k0);
            gload16(&b_lds[buf][i * 4096 + wave * 512], srcB[i] + k0);
        }
    };

    f32x4 acc[4][2] = {};

    stage(0, 0);
    asm volatile("s_waitcnt vmcnt(0)" ::: "memory");
    __builtin_amdgcn_s_barrier();

    for (int t = 0; t < NT; ++t) {
        const int buf = t & 1;
        if (t + 1 < NT) stage(buf ^ 1, (t + 1) * 64);
#pragma unroll
        for (int ks = 0; ks < 2; ++ks) {
            short8 af[4], bfr[2];
#pragma unroll
            for (int mf = 0; mf < 4; ++mf) {
                int row = wm * 64 + mf * 16 + lr;
                int slot = (ks * 4 + lg) ^ (row & 7);
                af[mf] = *(const short8*)&a_lds[buf][row * 64 + slot * 8];
            }
#pragma unroll
            for (int nf = 0; nf < 2; ++nf) {
                int row = wn * 32 + nf * 16 + lr;
                int slot = (ks * 4 + lg) ^ (row & 7);
                bfr[nf] = *(const short8*)&b_lds[buf][row * 64 + slot * 8];
            }
#pragma unroll
            for (int mf = 0; mf < 4; ++mf)
#pragma unroll
                for (int nf = 0; nf < 2; ++nf)
                    acc[mf][nf] = __builtin_amdgcn_mfma_f32_16x16x32_bf16(af[mf], bfr[nf], acc[mf][nf], 0, 0, 0);
        }
        asm volatile("s_waitcnt vmcnt(0)" ::: "memory");
        __builtin_amdgcn_s_barrier();
    }

#pragma unroll
    for (int nf = 0; nf < 2; ++nf) {
        int gc = tn * 128 + wn * 32 + nf * 16 + lr;
        float bv = bias[gc];
        int part = 0, h = 0, dh = 0;
        if constexpr (EPI == 3) {
            part = gc / 768;
            int cc = gc - part * 768;
            h = cc / 96;
            dh = cc - h * 96;
        }
#pragma unroll
        for (int mf = 0; mf < 4; ++mf) {
            int grb = tm * 128 + wm * 64 + mf * 16 + lg * 4;
            if constexpr (EPI == 3) {
                int b = grb >> 10, n2 = grb & 1023;
                size_t bh = (size_t)(b * 8 + h);
                if (part == 2) {
                    ushort4 wv;
                    wv.x = f2b(acc[mf][nf][0] + bv);
                    wv.y = f2b(acc[mf][nf][1] + bv);
                    wv.z = f2b(acc[mf][nf][2] + bv);
                    wv.w = f2b(acc[mf][nf][3] + bv);
                    *(ushort4*)&v_o[(bh * 96 + dh) * 1024 + n2] = wv;
                } else {
                    unsigned short* dst = (part == 0) ? q_o : k_o;
                    float sc = (part == 0) ? 0.14724445f : 1.f;
#pragma unroll
                    for (int r = 0; r < 4; ++r)
                        dst[(bh * 1024 + n2 + r) * 96 + dh] = f2b((acc[mf][nf][r] + bv) * sc);
                }
            } else {
#pragma unroll
                for (int r = 0; r < 4; ++r) {
                    int gr = grb + r;
                    float v = acc[mf][nf][r] + bv;
                    if constexpr (EPI == 0) {
                        outf[(size_t)gr * N + gc] = v;
                    } else if constexpr (EPI == 1) {
                        outb[(size_t)gr * N + gc] = f2b(v);
                    } else {
                        float gl = 0.5f * v * (1.f + erff(v * 0.70710678f));
                        outb[(size_t)gr * N + gc] = f2b(gl);
                    }
                }
            }
        }
    }
}

// ---------------- flash attention: swapped QK^T, hoisted cjmm, folded flat-re, T5 ------
__global__ __launch_bounds__(512, 4) void attn_kernel(
    const unsigned short* __restrict__ Qb, const unsigned short* __restrict__ Kb,
    const unsigned short* __restrict__ Vt, const float* __restrict__ centers,
    const int* __restrict__ types, const int* __restrict__ nmask,
    const float* __restrict__ tt, const float* __restrict__ rel_emb,
    unsigned short* __restrict__ Y) {
    __shared__ unsigned short kv_lds[2 * 12288];  // 48 KB
    __shared__ unsigned short p_lds[8 * 1024];    // 16 KB
    __shared__ float c_lds[1024];
    __shared__ unsigned int bab_lds[1024];
    __shared__ float rel_lds[41];
    __shared__ float cjmm_lds[32];

    const int tid = threadIdx.x;
    const int wave = tid >> 6, lane = tid & 63;
    const int lr = lane & 15, lg = lane >> 4;
    const int bh = blockIdx.x, qb = blockIdx.y;
    const int b = bh >> 3, h = bh & 7;
    const int q0 = qb * 128 + wave * 16;
    const size_t kvbase = (size_t)bh * 1024 * 96;

    c_lds[tid] = centers[b * 1024 + tid];
    c_lds[tid + 512] = centers[b * 1024 + 512 + tid];
    if (tid < 41) rel_lds[tid] = rel_emb[tid * 8 + h] * L2E;
    {
        const float t00 = tt[h * 4], t01 = tt[h * 4 + 1];
        const float t10 = tt[h * 4 + 2], t11 = tt[h * 4 + 3];
#pragma unroll
        for (int i = 0; i < 2; ++i) {
            int j = tid + i * 512;
            int tj = types[b * 1024 + j];
            int mk = nmask[b * 1024 + j];
            float bA = L2E * (t00 + (t01 - t00) * tj) + (mk ? 0.f : -1e30f);
            float bB = L2E * ((t10 - t00) + (t11 - t01 - t10 + t00) * tj);
            bab_lds[j] = (unsigned)f2b(bA) | ((unsigned)f2b(bB) << 16);
        }
    }

    const unsigned short* sbase[3];
    int sstep[3];
#pragma unroll
    for (int it = 0; it < 3; ++it) {
        int g = it * 512 + tid;
        if (g < 768) {  // K granule
            int ks = g >> 8, rem = g & 255, pr = rem >> 3, sl = rem & 7;
            int so = sl ^ (pr & 7);
            int r = ((so >> 2) << 5) + pr, oct = so & 3;
            sbase[it] = Kb + kvbase + (size_t)r * 96 + ks * 32 + oct * 8;
            sstep[it] = 64 * 96;
        } else {  // V granule
            int gv = g - 768, pr = gv >> 3, sl = gv & 7;
            int so = sl ^ (pr & 7);
            sbase[it] = Vt + (size_t)(bh * 96 + pr) * 1024 + so * 8;
            sstep[it] = 64;
        }
    }
    auto stage = [&](int bufb, int kt) {
        unsigned short* dst = kv_lds + bufb * 12288;
#pragma unroll
        for (int it = 0; it < 3; ++it)
            gload16(dst + it * 4096 + wave * 512, sbase[it] + (size_t)kt * sstep[it]);
    };

    short8 qa[3];
#pragma unroll
    for (int ks = 0; ks < 3; ++ks)
        qa[ks] = *(const short8*)&Qb[kvbase + (size_t)(q0 + lr) * 96 + ks * 32 + lg * 8];
    short8 qa3 = {};
    {
        int ti0 = types[b * 1024 + q0 + lr];
        if (lg == 0) {
            qa3[0] = (short)0x3F80;
            qa3[1] = ti0 ? (short)0x3F80 : (short)0;
        }
    }
    const float ci20 = centers[b * 1024 + q0 + lr] + 20.f;
    float cimax20 = ci20, cimin20 = ci20;
#pragma unroll
    for (int off = 1; off < 16; off <<= 1) {
        cimax20 = fmaxf(cimax20, __shfl_xor(cimax20, off));
        cimin20 = fminf(cimin20, __shfl_xor(cimin20, off));
    }

    float m_s = -3e30f, l_s = 0.f;
    f32x4 oacc[6] = {};
    unsigned* p32 = (unsigned*)&p_lds[wave * 1024];

    stage(0, 0);
    asm volatile("s_waitcnt lgkmcnt(0)" ::: "memory");
    __builtin_amdgcn_s_barrier();

    if (tid < 256) {
        int ktt = tid >> 4;
        float4 cv = *(const float4*)&c_lds[ktt * 64 + (tid & 15) * 4];
        float mn = fminf(fminf(cv.x, cv.y), fminf(cv.z, cv.w));
        float mx = fmaxf(fmaxf(cv.x, cv.y), fmaxf(cv.z, cv.w));
#pragma unroll
        for (int off = 1; off < 16; off <<= 1) {
            mn = fminf(mn, __shfl_xor(mn, off));
            mx = fmaxf(mx, __shfl_xor(mx, off));
        }
        if ((tid & 15) == 0) { cjmm_lds[ktt] = mn; cjmm_lds[16 + ktt] = mx; }
    }
    asm volatile("s_waitcnt lgkmcnt(0)" ::: "memory");
    const float rel0v = rel_lds[0], rel40v = rel_lds[40];

    for (int kt = 0; kt < 16; ++kt) {
        const int buf = kt & 1;
        if (kt < 15) {
            stage(buf ^ 1, kt + 1);
            asm volatile("s_waitcnt vmcnt(3)" ::: "memory");
        } else {
            asm volatile("s_waitcnt vmcnt(0)" ::: "memory");
        }
        __builtin_amdgcn_s_barrier();
        const unsigned short* kv = kv_lds + buf * 12288;

        f32x4 s[4] = {};
        __builtin_amdgcn_s_setprio(1);
#pragma unroll
        for (int jf = 0; jf < 4; ++jf) {
            int pr = ((jf & 1) << 4) + lr;
            int slp = (((jf >> 1) << 2) + lg) ^ (lr & 7);
#pragma unroll
            for (int ks = 0; ks < 3; ++ks) {
                short8 kf = *(const short8*)&kv[ks * 2048 + pr * 64 + slp * 8];
                s[jf] = __builtin_amdgcn_mfma_f32_16x16x32_bf16(kf, qa[ks], s[jf], 0, 0, 0);
            }
            unsigned vb = bab_lds[kt * 64 + jf * 16 + lr];
            short8 kf3 = {};
            if (lg == 0) {
                kf3[0] = (short)(vb & 0xffffu);
                kf3[1] = (short)(vb >> 16);
            }
            s[jf] = __builtin_amdgcn_mfma_f32_16x16x32_bf16(kf3, qa3, s[jf], 0, 0, 0);
        }
        __builtin_amdgcn_s_setprio(0);

        float re_eff;
        {
            float cjmn = cjmm_lds[kt], cjmx = cjmm_lds[16 + kt];
            bool flatHi = (cimin20 - cjmx >= 40.f);
            bool flatLo = (cimax20 - cjmn <= 0.f);
            if (flatHi || flatLo) {
                re_eff = flatHi ? rel40v : rel0v;
            } else {
                re_eff = 0.f;
#pragma unroll
                for (int jf = 0; jf < 4; ++jf) {
                    float4 cj4 = *(const float4*)&c_lds[kt * 64 + jf * 16 + lg * 4];
                    float cjl[4] = {cj4.x, cj4.y, cj4.z, cj4.w};
#pragma unroll
                    for (int r = 0; r < 4; ++r) {
                        float idxf = __builtin_amdgcn_fmed3f(ci20 - cjl[r], 0.f, 40.f);
                        s[jf][r] += rel_lds[(int)rintf(idxf)];
                    }
                }
            }
        }

        {
            float mlr = s[0][0];
#pragma unroll
            for (int jf = 0; jf < 4; ++jf)
#pragma unroll
                for (int r = 0; r < 4; ++r) mlr = fmaxf(mlr, s[jf][r]);
            float mb = m_s - re_eff;
            if (!__all(mlr <= mb + 8.f)) {
                float mx = fmaxf(mlr, __shfl_xor(mlr, 16));
                mx = fmaxf(mx, __shfl_xor(mx, 32));
                mx += re_eff;
                float mn = fmaxf(m_s, mx);
                float al = exp2v(m_s - mn);
                m_s = mn;
                l_s *= al;
#pragma unroll
                for (int r = 0; r < 4; ++r) {
                    float alr = __shfl(al, lg * 4 + r);
#pragma unroll
                    for (int nf = 0; nf < 6; ++nf) oacc[nf][r] *= alr;
                }
                mb = m_s - re_eff;
            }
            float ls = 0.f;
#pragma unroll
            for (int jf = 0; jf < 4; ++jf)
#pragma unroll
                for (int r = 0; r < 4; ++r) {
                    s[jf][r] = exp2v(s[jf][r] - mb);
                    ls += s[jf][r];
                }
            ls += __shfl_xor(ls, 16);
            ls += __shfl_xor(ls, 32);
            l_s += ls;
        }

#pragma unroll
        for (int jf = 0; jf < 4; ++jf) {
            uint2 w2;
            w2.x = cvt_pk_bf16(s[jf][0], s[jf][1]);
            w2.y = cvt_pk_bf16(s[jf][2], s[jf][3]);
            int gsw = ((jf * 4 + lg) ^ (lr & 14)) * 2;
            *(uint2*)&p32[lr * 32 + gsw] = w2;
        }
        asm volatile("s_waitcnt lgkmcnt(0)" ::: "memory");
        short8 pa[2];
#pragma unroll
        for (int js = 0; js < 2; ++js) {
            int gsw = (((js * 8 + lg * 2) ^ (lr & 14))) * 2;
            pa[js] = *(const short8*)&p32[lr * 32 + gsw];
        }

        __builtin_amdgcn_s_setprio(1);
#pragma unroll
        for (int nf = 0; nf < 6; ++nf) {
            int vrow = nf * 16 + lr;
#pragma unroll
            for (int js = 0; js < 2; ++js) {
                int slp = ((js << 2) + lg) ^ (lr & 7);
                short8 vf = *(const short8*)&kv[6144 + vrow * 64 + slp * 8];
                oacc[nf] = __builtin_amdgcn_mfma_f32_16x16x32_bf16(pa[js], vf, oacc[nf], 0, 0, 0);
            }
        }
        __builtin_amdgcn_s_setprio(0);
        __builtin_amdgcn_s_barrier();
    }

#pragma unroll
    for (int r = 0; r < 4; ++r) {
        float lrow = __shfl(l_s, lg * 4 + r);
        float inv = (lrow > 0.f) ? 1.f / lrow : 0.f;
        int qi = q0 + lg * 4 + r;
#pragma unroll
        for (int nf = 0; nf < 6; ++nf)
            Y[((size_t)b * 1024 + qi) * 768 + h * 96 + nf * 16 + lr] = f2b(oacc[nf][r] * inv);
    }
}

// ---------------- layernorm with residual add (vectorized, 2 rows/block) ----------------
template <bool IN1BF, bool IN2BF>
__global__ __launch_bounds__(384) void ln_kernel(const void* __restrict__ in1,
                                                 const void* __restrict__ in2,
                                                 const float* __restrict__ g,
                                                 const float* __restrict__ be,
                                                 float* __restrict__ of,
                                                 unsigned short* __restrict__ ob) {
    const int tid = threadIdx.x;
    const int half = tid / 192;
    const int t = tid - half * 192;
    const int row = blockIdx.x * 2 + half;
    const size_t base = (size_t)row * 768 + t * 4;
    float a[4], bb[4];
    if (IN1BF) {
        ushort4 u = *(const ushort4*)((const unsigned short*)in1 + base);
        a[0] = b2f(u.x); a[1] = b2f(u.y); a[2] = b2f(u.z); a[3] = b2f(u.w);
    } else {
        float4 u = *(const float4*)((const float*)in1 + base);
        a[0] = u.x; a[1] = u.y; a[2] = u.z; a[3] = u.w;
    }
    if (IN2BF) {
        ushort4 u = *(const ushort4*)((const unsigned short*)in2 + base);
        bb[0] = b2f(u.x); bb[1] = b2f(u.y); bb[2] = b2f(u.z); bb[3] = b2f(u.w);
    } else {
        float4 u = *(const float4*)((const float*)in2 + base);
        bb[0] = u.x; bb[1] = u.y; bb[2] = u.z; bb[3] = u.w;
    }
    float v[4];
#pragma unroll
    for (int i = 0; i < 4; ++i) v[i] = a[i] + bb[i];
    float s1 = v[0] + v[1] + v[2] + v[3];
    float s2 = v[0] * v[0] + v[1] * v[1] + v[2] * v[2] + v[3] * v[3];
#pragma unroll
    for (int off = 32; off > 0; off >>= 1) {
        s1 += __shfl_xor(s1, off);
        s2 += __shfl_xor(s2, off);
    }
    __shared__ float red[12];
    const int wv = tid >> 6;
    if ((tid & 63) == 0) { red[wv] = s1; red[6 + wv] = s2; }
    __syncthreads();
    const int w0 = half * 3;
    s1 = red[w0] + red[w0 + 1] + red[w0 + 2];
    s2 = red[6 + w0] + red[6 + w0 + 1] + red[6 + w0 + 2];
    float mu = s1 * (1.f / 768.f);
    float var = s2 * (1.f / 768.f) - mu * mu;
    float inv = rsqrtf(var + 1e-5f);
    float o[4];
#pragma unroll
    for (int i = 0; i < 4; ++i)
        o[i] = (v[i] - mu) * inv * g[t * 4 + i] + be[t * 4 + i];
    if (of) {
        float4 w = {o[0], o[1], o[2], o[3]};
        *(float4*)(of + base) = w;
    }
    if (ob) {
        ushort4 w = {f2b(o[0]), f2b(o[1]), f2b(o[2]), f2b(o[3])};
        *(ushort4*)(ob + base) = w;
    }
}

extern "C" void kernel_launch(void* const* d_in, const int* in_sizes, int n_in,
                              void* d_out, int out_size, void* d_ws, size_t ws_size,
                              hipStream_t stream) {
    const float* x     = (const float*)d_in[0];
    const int*   nmask = (const int*)d_in[1];
    const float* cent  = (const float*)d_in[2];
    const int*   types = (const int*)d_in[3];
    const float* qkv_w = (const float*)d_in[4];
    const float* qkv_b = (const float*)d_in[5];
    const float* out_w = (const float*)d_in[6];
    const float* out_b = (const float*)d_in[7];
    const float* ff1_w = (const float*)d_in[8];
    const float* ff1_b = (const float*)d_in[9];
    const float* ff2_w = (const float*)d_in[10];
    const float* ff2_b = (const float*)d_in[11];
    const float* ln1_g = (const float*)d_in[12];
    const float* ln1_b = (const float*)d_in[13];
    const float* ln2_g = (const float*)d_in[14];
    const float* ln2_b = (const float*)d_in[15];
    const float* rel   = (const float*)d_in[16];
    const float* ttp   = (const float*)d_in[17];

    char* w = (char*)d_ws;
    auto alloc = [&](size_t bytes) {
        char* p = w;
        w += (bytes + 255) & ~(size_t)255;
        return p;
    };
    unsigned short* xb  = (unsigned short*)alloc(8192ull * 768 * 2);   // x bf16 (NOT clobbered)
    unsigned short* yb  = (unsigned short*)alloc(8192ull * 768 * 2);   // attn output Y
    unsigned short* qwT = (unsigned short*)alloc(2304ull * 768 * 2);
    unsigned short* owT = (unsigned short*)alloc(768ull * 768 * 2);
    unsigned short* f1T = (unsigned short*)alloc(1024ull * 768 * 2);
    unsigned short* f2T = (unsigned short*)alloc(768ull * 1024 * 2);
    unsigned short* Qb  = (unsigned short*)alloc(64ull * 1024 * 96 * 2);
    unsigned short* Kb  = (unsigned short*)alloc(64ull * 1024 * 96 * 2);
    unsigned short* Vt  = (unsigned short*)alloc(64ull * 96 * 1024 * 2);
    unsigned short* aob = (unsigned short*)alloc(8192ull * 768 * 2);  // residual branch (bf16)
    unsigned short* h1b = (unsigned short*)alloc(8192ull * 768 * 2);
    unsigned short* ffa = Qb;  // alias: ff1 act (16.8MB) spans Qb+Kb (25.2MB), both dead after attn

    // fused cvt + 4 transposes: 6144 + 3840 = 9984 blocks
    prep_kernel<<<9984, 256, 0, stream>>>(x, xb, qkv_w, qwT, out_w, owT,
                                          ff1_w, f1T, ff2_w, f2T);

    // QKV: M=8192 N=2304 K=768 -> 64x18 = 1152 blocks
    gemm2p<3><<<1152, 512, 0, stream>>>(xb, qwT, qkv_b, nullptr, nullptr,
                                        Qb, Kb, Vt, 2304, 768, 18, 12);
    attn_kernel<<<dim3(64, 8), 512, 0, stream>>>(Qb, Kb, Vt, cent, types, nmask, ttp, rel, yb);
    // out proj: N=768 K=768 -> 384 blocks, bf16 out
    gemm2p<1><<<384, 512, 0, stream>>>(yb, owT, out_b, nullptr, aob,
                                       nullptr, nullptr, nullptr, 768, 768, 6, 12);
    ln_kernel<true, true><<<4096, 384, 0, stream>>>(xb, aob, ln1_g, ln1_b, nullptr, h1b);
    // ff1+gelu: N=1024 K=768 -> 512 blocks
    gemm2p<2><<<512, 512, 0, stream>>>(h1b, f1T, ff1_b, nullptr, ffa,
                                       nullptr, nullptr, nullptr, 1024, 768, 8, 12);
    // ff2: N=768 K=1024 -> 384 blocks, NT=16, bf16 out (reuse aob)
    gemm2p<1><<<384, 512, 0, stream>>>(ffa, f2T, ff2_b, nullptr, aob,
                                       nullptr, nullptr, nullptr, 768, 1024, 6, 16);
    ln_kernel<true, true><<<4096, 384, 0, stream>>>(h1b, aob, ln2_g, ln2_b, (float*)d_out, nullptr);
}